// Round 12
// baseline (96.650 us; speedup 1.0000x reference)
//
#include <hip/hip_runtime.h>
#include <hip/hip_bf16.h>
#include <math.h>

// LOGG3D_ATTN, MFMA flash-attention v12.
//   topK==1 -> top_k is a permutation -> SOP permutation-invariant -> skipped.
//   /k and L2-norm cancel -> M = sum w_i^2 f_i f_i^T, normalized.
//   exp never overflows (s/4 <= ~14) -> no online max; partials linear in j.
// v12 = v9-proven math, grids reshaped only (v10/v11's restructured wsop +
// bf16 partials failed twice with identical error; reverted wholesale):
//   - attn: v9's 64-row-wave kernel, JSPLIT=16, JT=768 single-tile (one stage,
//     one barrier pair; 48KB LDS -> 3 blocks/CU), f32 ctx partials (12.6 MB).
//   - wsop: 768 blocks x 64 threads; per-wave code identical to v9's
//     weights_sop (rl=lane>>2, q=lane&3, serial js loop, shfl_xor 1,2);
//     SOP emits 4 outputs/thread.
//   - finalize: 1024-thread reduce (v7-derived), bound 768.

#define NP 12288
#define JSPLIT 16
#define JCHUNK (NP / JSPLIT)   // 768
#define JT JCHUNK              // single tile
#define JGPT (JT / 16)         // 48
#define NBLK2 768              // wsop grid

// 0.25 * log2(e)
#define QSCALE 0.3606737602222839f

typedef __attribute__((ext_vector_type(4))) float f32x4;
typedef __attribute__((ext_vector_type(2))) unsigned u32x2;
typedef __attribute__((ext_vector_type(8))) short s16x8;
typedef __attribute__((ext_vector_type(4))) short s16x4;

#if defined(__has_builtin)
#if __has_builtin(__builtin_amdgcn_mfma_f32_16x16x16bf16_1k)
#define HAVE_MFMA16_BUILTIN 1
#endif
#if __has_builtin(__builtin_amdgcn_exp2f)
#define EXP2F(x) __builtin_amdgcn_exp2f(x)
#endif
#if __has_builtin(__builtin_amdgcn_perm)
#define HAVE_PERM 1
#endif
#endif
#ifndef EXP2F
#define EXP2F(x) exp2f(x)
#endif

static __device__ __forceinline__ f32x4 mfma16(s16x4 a, s16x4 b, f32x4 c) {
#ifdef HAVE_MFMA16_BUILTIN
    return __builtin_amdgcn_mfma_f32_16x16x16bf16_1k(a, b, c, 0, 0, 0);
#else
    f32x4 d;
    asm volatile("s_nop 1\n\t"
                 "v_mfma_f32_16x16x16_bf16 %0, %1, %2, %0"
                 : "=v"(d)
                 : "v"(a), "v"(b), "0"(c));
    return d;
#endif
}

static __device__ __forceinline__ short f2bf(float x) {
    __hip_bfloat16 h = __float2bfloat16(x);
    return __builtin_bit_cast(short, h);
}

// 4x f32 -> 4x bf16, round-half-up: (bits + 0x8000) >> 16, pair-packed.
static __device__ __forceinline__ s16x4 pack_rhu(f32x4 e) {
    const unsigned u0 = __builtin_bit_cast(unsigned, e[0]) + 0x8000u;
    const unsigned u1 = __builtin_bit_cast(unsigned, e[1]) + 0x8000u;
    const unsigned u2 = __builtin_bit_cast(unsigned, e[2]) + 0x8000u;
    const unsigned u3 = __builtin_bit_cast(unsigned, e[3]) + 0x8000u;
    u32x2 t;
#ifdef HAVE_PERM
    t[0] = __builtin_amdgcn_perm(u1, u0, 0x07060302u);
    t[1] = __builtin_amdgcn_perm(u3, u2, 0x07060302u);
#else
    t[0] = (u0 >> 16) | (u1 & 0xFFFF0000u);
    t[1] = (u2 >> 16) | (u3 & 0xFFFF0000u);
#endif
    return __builtin_bit_cast(s16x4, t);
}

static __device__ __forceinline__ f32x4 exp4(f32x4 s) {
    f32x4 e;
    e[0] = EXP2F(s[0]); e[1] = EXP2F(s[1]);
    e[2] = EXP2F(s[2]); e[3] = EXP2F(s[3]);
    return e;
}

// ---------------- prep: fp32 feats -> bf16 operands ----------------
__global__ __launch_bounds__(256)
void prep(const float* __restrict__ feats,
          unsigned short* __restrict__ ghi, unsigned short* __restrict__ shi,
          unsigned short* __restrict__ gFt)
{
    __shared__ unsigned short tr[64 * 16];       // 2 KB
    const int tid = threadIdx.x;
    const int rowbase = blockIdx.x * 64;         // 192 blocks x 64 rows

    const f32x4 v = *(const f32x4*)(feats + (size_t)rowbase * 16 + tid * 4);
    s16x4 hv, sv;
    #pragma unroll
    for (int k = 0; k < 4; ++k) {
        hv[k] = f2bf(v[k]);
        sv[k] = f2bf(v[k] * QSCALE);
    }
    *(s16x4*)(ghi + (size_t)rowbase * 16 + tid * 4) = hv;
    *(s16x4*)(shi + (size_t)rowbase * 16 + tid * 4) = sv;
    *(s16x4*)(tr + (tid >> 2) * 16 + (tid & 3) * 4) = hv;
    __syncthreads();

    if (tid < 128) {
        const int p = tid >> 3, q8 = tid & 7;    // plane, 8-row group
        s16x8 o;
        #pragma unroll
        for (int e = 0; e < 8; ++e) o[e] = (short)tr[(q8 * 8 + e) * 16 + p];
        *(s16x8*)(gFt + (size_t)p * NP + rowbase + q8 * 8) = o;
    }
}

// ---------------- kernel 1: MFMA flash attention partials ----------------
__global__ __launch_bounds__(256)
void attn_mfma(const unsigned short* __restrict__ ghi,
               const unsigned short* __restrict__ shi,
               const unsigned short* __restrict__ gFt,
               float* __restrict__ ctx_part,   // [JSPLIT][N][16] f32
               float* __restrict__ l_part)     // [JSPLIT][N]
{
    __shared__ unsigned short hiT[JT * 16];   // 24 KB, row-XOR-swizzled
    __shared__ unsigned short FtT[16 * JT];   // 24 KB, plane-XOR-swizzled

    const int tid = threadIdx.x;
    const int wave = tid >> 6, lane = tid & 63;
    const int il = lane & 15, g = lane >> 4, g4 = g * 4, g8 = g * 8;
    const int js = blockIdx.x & (JSPLIT - 1);
    const int rowblk = blockIdx.x >> 4;              // 0..47
    const int ibase = rowblk * 256 + wave * 64;      // wave owns 64 i-rows
    const int jbase = js * JCHUNK;

    // 4 i-side B fragments (prescaled), constant over the loop
    s16x4 bF[4];
    #pragma unroll
    for (int t = 0; t < 4; ++t)
        bF[t] = *(const s16x4*)(shi + (size_t)(ibase + t * 16 + il) * 16 + g4);

    s16x4 ones; ones[0] = ones[1] = ones[2] = ones[3] = (short)0x3F80;
    const f32x4 kZero = {0.f, 0.f, 0.f, 0.f};
    f32x4 ctx[4], lacc[4];
    #pragma unroll
    for (int t = 0; t < 4; ++t) { ctx[t] = kZero; lacc[t] = kZero; }

    const char* aBase = (const char*)hiT + ((il * 32 + g8) ^ ((il & 7) << 4));
    const char* vPlane = (const char*)FtT + il * (JT * 2);
    const int vKey = (il & 7) << 4;

    const int fp = tid >> 4, fq = tid & 15;          // Ft staging: plane, chunk

    // ---- stage the single 768-row j-tile (swizzle at write) ----
    {
        const char* gH = (const char*)ghi + (size_t)jbase * 32;
        #pragma unroll
        for (int k = 0; k < 6; ++k) {                // 1536 chunks of 16B
            const int c = tid + (k << 8);
            s16x8 v = *(const s16x8*)(gH + c * 16);
            *(s16x8*)((char*)hiT + ((c * 16) ^ (((c >> 1) & 7) << 4))) = v;
        }
        const char* gF = (const char*)gFt + (size_t)fp * (NP * 2) + (size_t)jbase * 2;
        #pragma unroll
        for (int k = 0; k < 6; ++k) {                // 96 chunks per plane
            const int cq = fq + (k << 4);
            s16x8 v = *(const s16x8*)(gF + cq * 16);
            *(s16x8*)((char*)FtT + fp * (JT * 2)
                      + ((cq * 16) ^ ((fp & 7) << 4))) = v;
        }
    }
    __syncthreads();

    #pragma unroll 2
    for (int jg = 0; jg < JGPT; ++jg) {
        const s16x4 aS = *(const s16x4*)(aBase + jg * 512);
        const s16x4 aV = *(const s16x4*)(vPlane + (((jg << 5) + g8) ^ vKey));
        #pragma unroll
        for (int t = 0; t < 4; ++t) {
            const f32x4 s = mfma16(aS, bF[t], kZero);   // S^T * log2e/4
            const s16x4 p = pack_rhu(exp4(s));
            ctx[t]  = mfma16(aV, p, ctx[t]);            // ctx^T partial
            lacc[t] = mfma16(ones, p, lacc[t]);         // row-sum l
        }
    }

    asm volatile("s_nop 7\n\ts_nop 7" ::: );

    #pragma unroll
    for (int t = 0; t < 4; ++t) {
        const int iT = ibase + t * 16 + il;
        *(f32x4*)(ctx_part + ((size_t)js * NP + iT) * 16 + g4) = ctx[t];
        if (g == 0) l_part[(size_t)js * NP + iT] = lacc[t][0];
    }
}

// ---- kernel 2: js-reduce + weights + per-16-row SOP partial (768 x 64) ----
// Per-wave math identical to v9's weights_sop (passing): rl=lane>>2, q=lane&3,
// serial js loop for c and l, shfl_xor(1,2) z-reduce.
__global__ __launch_bounds__(64)
void wsop(const float* __restrict__ feats,
          const float* __restrict__ ctxp,
          const float* __restrict__ lp,
          float* __restrict__ mpart)      // [NBLK2][256]
{
    __shared__ float gw[16][17];
    const int tid = threadIdx.x;           // 0..63, one wave
    const int rl = tid >> 2, q = tid & 3, d0 = q * 4;
    const int row = blockIdx.x * 16 + rl;

    f32x4 c = {0.f, 0.f, 0.f, 0.f};
    float l = 0.f;
    #pragma unroll
    for (int js = 0; js < JSPLIT; ++js) {
        c += *(const f32x4*)(ctxp + ((size_t)js * NP + row) * 16 + d0);
        l += lp[(size_t)js * NP + row];
    }
    const f32x4 fv = *(const f32x4*)(feats + (size_t)row * 16 + d0);
    float zp = c[0]*fv[0] + c[1]*fv[1] + c[2]*fv[2] + c[3]*fv[3];
    zp += __shfl_xor(zp, 1, 64);
    zp += __shfl_xor(zp, 2, 64);
    const float z = zp / l;
    const float w = 1.f / (1.f + EXP2F(-z * 1.4426950408889634f));

    gw[rl][d0 + 0] = w * fv[0];
    gw[rl][d0 + 1] = w * fv[1];
    gw[rl][d0 + 2] = w * fv[2];
    gw[rl][d0 + 3] = w * fv[3];
    __syncthreads();

    // SOP partial over this block's 16 rows: 4 outputs per thread
    #pragma unroll
    for (int k = 0; k < 4; ++k) {
        const int idx = tid * 4 + k;
        const int dd = idx >> 4, ee = idx & 15;
        float acc = 0.f;
        #pragma unroll
        for (int r = 0; r < 16; ++r) acc += gw[r][dd] * gw[r][ee];
        mpart[(size_t)blockIdx.x * 256 + idx] = acc;
    }
}

// ---------------- kernel 3: reduce + L2 normalize (1024 threads) -------------
__global__ __launch_bounds__(1024)
void finalize(const float* __restrict__ mpart, float* __restrict__ out)
{
    __shared__ float part[1024];
    __shared__ float red[4];
    const int tid = threadIdx.x;
    const int o = tid & 255, s = tid >> 8;       // output elem, slice 0..3

    float m = 0.f;
    #pragma unroll 8
    for (int b = s; b < NBLK2; b += 4) m += mpart[(size_t)b * 256 + o];
    part[tid] = m;
    __syncthreads();

    if (tid < 256) {
        m = part[tid] + part[tid + 256] + part[tid + 512] + part[tid + 768];
        float ss = m * m;
        #pragma unroll
        for (int msk = 32; msk >= 1; msk >>= 1) ss += __shfl_xor(ss, msk, 64);
        if ((tid & 63) == 0) red[tid >> 6] = ss;
    }
    __syncthreads();
    if (tid < 256) {
        const float tot = red[0] + red[1] + red[2] + red[3];
        out[tid] = m / sqrtf(tot);
    }
}

extern "C" void kernel_launch(void* const* d_in, const int* in_sizes, int n_in,
                              void* d_out, int out_size, void* d_ws, size_t ws_size,
                              hipStream_t stream) {
    (void)n_in; (void)out_size; (void)ws_size;
    const float* feats = (const float*)d_in[0];
    // d_in[1] (topK==1): k==N -> top-k is a no-op for the SOP.

    char* w = (char*)d_ws;
    unsigned short* ghi = (unsigned short*)(w);                  //   393216 B
    unsigned short* shi = (unsigned short*)(w + 393216);         //   393216 B
    unsigned short* gFt = (unsigned short*)(w + 786432);         //   393216 B
    float* ctxp = (float*)(w + 1179648);                         // 12582912 B
    float* lp   = (float*)(w + 13762560);                        //   786432 B
    float* mp   = (float*)(w + 14548992);                        //   786432 B
    // total 15335424 B

    prep     <<<192,   256, 0, stream>>>(feats, ghi, shi, gFt);
    attn_mfma<<<768,   256, 0, stream>>>(ghi, shi, gFt, ctxp, lp);
    wsop     <<<NBLK2,  64, 0, stream>>>(feats, ctxp, lp, mp);
    finalize <<<1,    1024, 0, stream>>>(mp, (float*)d_out);
}